// Round 1
// baseline (186.762 us; speedup 1.0000x reference)
//
#include <hip/hip_runtime.h>
#include <cmath>

// Diagonal linear recurrence: y[l][h] = exp(tau[h]) * y[l-1][h] + x[l][h]
// Two-pass chunked scan. L=16384, H=1024, fp32.
//
// Pass 1: per (chunk c, channel h) compute e_c[h] = sum_i lam^(T-1-i) x[cT+i]
// Pass 2: per (chunk c, channel h) reconstruct carry via lookback over e_{c'<c}
//         with multiplier lam^T, then replay local recurrence and write y.

static constexpr int TC = 64;   // chunk length along L  (C = L/TC = 256 chunks)

__global__ __launch_bounds__(256)
void li_chunk_ends(const float* __restrict__ x, const float* __restrict__ tau,
                   float* __restrict__ ends, int H) {
    const int h = blockIdx.x * blockDim.x + threadIdx.x;   // channel
    const int c = blockIdx.y;                              // chunk
    const float lam = expf(tau[h]);
    const float* xp = x + (size_t)c * TC * H + h;
    float s = 0.0f;
#pragma unroll
    for (int i = 0; i < TC; ++i)
        s = fmaf(lam, s, xp[(size_t)i * H]);               // coalesced across h
    ends[(size_t)c * H + h] = s;
}

__global__ __launch_bounds__(256)
void li_final(const float* __restrict__ x, const float* __restrict__ tau,
              const float* __restrict__ ends, float* __restrict__ y, int H) {
    const int h = blockIdx.x * blockDim.x + threadIdx.x;
    const int c = blockIdx.y;
    const float t   = tau[h];
    const float lam  = expf(t);
    const float lamT = expf(t * (float)TC);   // lam^TC, exact via exp(T*tau)

    // Lookback: carry = y[c*TC - 1] = scan of chunk-end values with factor lamT.
    float carry = 0.0f;
    for (int cc = 0; cc < c; ++cc)
        carry = fmaf(lamT, carry, ends[(size_t)cc * H + h]);  // 1 MB hot set, L2 hits

    const size_t base = (size_t)c * TC * H + h;
    float s = carry;
#pragma unroll
    for (int i = 0; i < TC; ++i) {
        s = fmaf(lam, s, x[base + (size_t)i * H]);
        y[base + (size_t)i * H] = s;
    }
}

extern "C" void kernel_launch(void* const* d_in, const int* in_sizes, int n_in,
                              void* d_out, int out_size, void* d_ws, size_t ws_size,
                              hipStream_t stream) {
    const float* x   = (const float*)d_in[0];
    const float* tau = (const float*)d_in[1];
    float* y = (float*)d_out;

    const int H = in_sizes[1];       // 1024
    const int L = in_sizes[0] / H;   // 16384
    const int C = L / TC;            // 256

    float* ends = (float*)d_ws;      // C*H floats = 1 MB scratch (fully overwritten)

    dim3 block(256);
    dim3 grid(H / 256, C);           // (4, 256) = 1024 blocks, 16 waves/CU
    li_chunk_ends<<<grid, block, 0, stream>>>(x, tau, ends, H);
    li_final   <<<grid, block, 0, stream>>>(x, tau, ends, y, H);
}